// Round 4
// baseline (250.906 us; speedup 1.0000x reference)
//
#include <hip/hip_runtime.h>
#include <math.h>

// CopyMamba3LM, token-id factorization (round 5, resubmitted round 6 —
// round-5 bench died in the container broker before compile; no data).
// Budget model (confirmed R4->R5): timed region = 2 harness poison fills
// (~193 us, 604 MB @6.2 TB/s each, immovable) + ~44 us of our kernels.
// Floor: 151 MB output stores ~= 24 us. Addressable: ~15 us.
// R5 changes:
//  - ktok: token-tile x4 (64 blocks). LN per-wave (no barriers), e4/w4
//    loads reused across 4 tokens -> L2 reads 190->48 MB, barriers 16->2.
//  - kfused: single-wave 64-thread blocks, 4 vocab/thread. Softmax via
//    wave shuffles only; attn slice in 8 f4v regs; logmix packed to one
//    f4v/lane; store loop = 9 NT dwordx4 per lane per row.
//  - kprep untouched (holds the scan/scatter).
// Decision rule: dur >= 234 => at poison+store floor, declare roofline.

#define DM 512
#define VC 256
#define SL 2048
#define NB 8
#define AD 64

typedef float f4v __attribute__((ext_vector_type(4)));

__device__ __forceinline__ float wave_sum(float v) {
#pragma unroll
  for (int o = 32; o > 0; o >>= 1) v += __shfl_xor(v, o, 64);
  return v;
}
__device__ __forceinline__ float wave_max(float v) {
#pragma unroll
  for (int o = 32; o > 0; o >>= 1) v = fmaxf(v, __shfl_xor(v, o, 64));
  return v;
}
__device__ __forceinline__ float hsum4(float4 a) {
  return a.x + a.y + a.z + a.w;
}
__device__ __forceinline__ float4 subs4(float4 a, float s) {
  float4 r; r.x = a.x - s; r.y = a.y - s; r.z = a.z - s; r.w = a.w - s;
  return r;
}
__device__ __forceinline__ float dot44(float4 a, float4 b) {
  return a.x * b.x + a.y * b.y + a.z * b.z + a.w * b.w;
}
__device__ __forceinline__ float4 lnmap4(float4 d, float inv, float4 g, float4 b) {
  float4 r;
  r.x = d.x * inv * g.x + b.x;
  r.y = d.y * inv * g.y + b.y;
  r.z = d.z * inv * g.z + b.z;
  r.w = d.w * inv * g.w + b.w;
  return r;
}

// K1: pack transposed operands + per-batch token histogram/scan/position-lists.
// (unchanged from R4 -- holds the verified scan/scatter)
__global__ __launch_bounds__(256) void kprep(
    const float* __restrict__ embed_w, const float* __restrict__ q_w,
    const float* __restrict__ k_w, const int* __restrict__ tokens,
    const int* __restrict__ prefix_lens,
    float* __restrict__ embed_P, float* __restrict__ qk_P,
    int* __restrict__ cnt, int* __restrict__ ncnt,
    int* __restrict__ offs, int* __restrict__ list)
{
  __shared__ int c[VC];    // masked (s < P) counts
  __shared__ int ca[VC];   // all-position counts
  __shared__ int off[VC];  // scan workspace -> exclusive offsets
  __shared__ int cur[VC];  // scatter cursors
  const int blk = blockIdx.x;
  const int tid = threadIdx.x;
  if (blk < DM) {
    const int d = blk;
    embed_P[(((d >> 2) * VC + tid) << 2) + (d & 3)] = embed_w[tid * DM + d];
    if (tid < 128) {
      float val = (tid < 64) ? q_w[tid * DM + d] : k_w[(tid - 64) * DM + d];
      qk_P[(((d >> 2) * 128 + tid) << 2) + (d & 3)] = val;
    }
  } else {
    const int b = blk - DM;
    c[tid] = 0; ca[tid] = 0;
    __syncthreads();
    const int P = prefix_lens[b];
    const int4* trow = (const int4*)(tokens + b * SL);
#pragma unroll
    for (int i = tid; i < SL / 4; i += 256) {
      int4 tk = trow[i];
      int s0 = i * 4;
      atomicAdd(&ca[tk.x], 1); atomicAdd(&ca[tk.y], 1);
      atomicAdd(&ca[tk.z], 1); atomicAdd(&ca[tk.w], 1);
      if (s0     < P && tk.x != 0) atomicAdd(&c[tk.x], 1);
      if (s0 + 1 < P && tk.y != 0) atomicAdd(&c[tk.y], 1);
      if (s0 + 2 < P && tk.z != 0) atomicAdd(&c[tk.z], 1);
      if (s0 + 3 < P && tk.w != 0) atomicAdd(&c[tk.w], 1);
    }
    __syncthreads();
    int myc = ca[tid];
    off[tid] = myc;
    __syncthreads();
    for (int d2 = 1; d2 < VC; d2 <<= 1) {
      int add = (tid >= d2) ? off[tid - d2] : 0;
      __syncthreads();
      off[tid] += add;
      __syncthreads();
    }
    int excl = off[tid] - myc;
    cur[tid] = excl;
    __syncthreads();
#pragma unroll
    for (int i = tid; i < SL / 4; i += 256) {
      int4 tk = trow[i];
      int s0 = i * 4;
      int p;
      p = atomicAdd(&cur[tk.x], 1); list[b * SL + p] = s0;
      p = atomicAdd(&cur[tk.y], 1); list[b * SL + p] = s0 + 1;
      p = atomicAdd(&cur[tk.z], 1); list[b * SL + p] = s0 + 2;
      p = atomicAdd(&cur[tk.w], 1); list[b * SL + p] = s0 + 3;
    }
    __syncthreads();
    cnt [b * VC + tid] = c[tid];
    ncnt[b * VC + tid] = myc;
    offs[b * VC + tid] = excl;
  }
}

// K2: token-tile x4. Block handles tokens t0..t0+3. Wave w computes LN+gate
// for token t0+w with wave-only reductions (lane l owns dims 4l..4l+3 and
// 256+4l..256+4l+3). Dot phase: thread=vocab v, each e4/w4 load feeds 4
// token-accumulators (per-token d4-ascending FP order preserved). Softmax:
// wave w reduces token t0+w from the lts tile.
__global__ __launch_bounds__(256) void ktok(
    const float* __restrict__ embed_w,
    const float* __restrict__ en_g, const float* __restrict__ en_b,
    const float* __restrict__ fn_g, const float* __restrict__ fn_b,
    const float* __restrict__ q_b, const float* __restrict__ k_b,
    const float* __restrict__ g_w, const float* __restrict__ g_b,
    const float* __restrict__ embed_P, const float* __restrict__ qk_P,
    float* __restrict__ q_tok, float* __restrict__ kT_P,
    float* __restrict__ gate_tok, float* __restrict__ probs_tok)
{
  __shared__ __align__(16) float hs[4 * DM];   // h for 4 tokens, 8 KB
  __shared__ __align__(16) float lts[4 * VC];  // logits tile, 4 KB
  const int t0 = blockIdx.x * 4;
  const int tid = threadIdx.x;
  const int w = tid >> 6;   // wave = token slot
  const int l = tid & 63;   // lane
  const int tt = t0 + w;

  // ---- LN phase (per-wave, no barriers) ----
  const float4* ew4 = (const float4*)(embed_w + (size_t)tt * DM);
  float4 x0 = ew4[l];
  float4 x1 = ew4[l + 64];
  float mu = wave_sum(hsum4(x0) + hsum4(x1)) * (1.0f / DM);
  float4 d0 = subs4(x0, mu), d1 = subs4(x1, mu);
  float var = wave_sum(dot44(d0, d0) + dot44(d1, d1)) * (1.0f / DM);
  float inv = 1.0f / sqrtf(var + 1e-5f);
  float4 y0 = lnmap4(d0, inv, ((const float4*)en_g)[l],      ((const float4*)en_b)[l]);
  float4 y1 = lnmap4(d1, inv, ((const float4*)en_g)[l + 64], ((const float4*)en_b)[l + 64]);
  mu = wave_sum(hsum4(y0) + hsum4(y1)) * (1.0f / DM);
  d0 = subs4(y0, mu); d1 = subs4(y1, mu);
  var = wave_sum(dot44(d0, d0) + dot44(d1, d1)) * (1.0f / DM);
  inv = 1.0f / sqrtf(var + 1e-5f);
  float4 h0 = lnmap4(d0, inv, ((const float4*)fn_g)[l],      ((const float4*)fn_b)[l]);
  float4 h1 = lnmap4(d1, inv, ((const float4*)fn_g)[l + 64], ((const float4*)fn_b)[l + 64]);
  // gate: lane-local dims cover all 512 within the wave
  float gp = wave_sum(dot44(h0, ((const float4*)g_w)[l]) +
                      dot44(h1, ((const float4*)g_w)[l + 64]));
  if (l == 0) gate_tok[tt] = 1.0f / (1.0f + expf(-(gp + g_b[0])));
  ((float4*)hs)[w * 128 + l]      = h0;
  ((float4*)hs)[w * 128 + 64 + l] = h1;
  __syncthreads();

  // ---- dot phase: thread = vocab v (and qk row for tid<128) ----
  const float4* hs4 = (const float4*)hs;
  const float4* e4p = (const float4*)embed_P;
  const float4* w4p = (const float4*)qk_P;
  const bool qk_lane = (tid < 128);  // wave-uniform
  float lt[4] = {0.f, 0.f, 0.f, 0.f};
  float aq[4] = {0.f, 0.f, 0.f, 0.f};
#pragma unroll 4
  for (int d4 = 0; d4 < DM / 4; ++d4) {
    float4 e4 = e4p[d4 * VC + tid];
    float4 hA = hs4[d4];
    float4 hB = hs4[128 + d4];
    float4 hC = hs4[256 + d4];
    float4 hD = hs4[384 + d4];
    lt[0] += dot44(hA, e4);
    lt[1] += dot44(hB, e4);
    lt[2] += dot44(hC, e4);
    lt[3] += dot44(hD, e4);
    if (qk_lane) {
      float4 w4 = w4p[d4 * 128 + tid];
      aq[0] += dot44(hA, w4);
      aq[1] += dot44(hB, w4);
      aq[2] += dot44(hC, w4);
      aq[3] += dot44(hD, w4);
    }
  }
  if (tid < 64) {
    float qb = q_b[tid];
#pragma unroll
    for (int t = 0; t < 4; ++t) q_tok[(t0 + t) * AD + tid] = aq[t] + qb;
  } else if (tid < 128) {
    int a = tid - 64;
    float kb = k_b[a];
#pragma unroll
    for (int t = 0; t < 4; ++t)
      kT_P[(((a >> 2) * VC + (t0 + t)) << 2) + (a & 3)] = aq[t] + kb;
  }
#pragma unroll
  for (int t = 0; t < 4; ++t) lts[t * VC + tid] = lt[t];
  __syncthreads();

  // ---- softmax: wave w handles token t0+w ----
  float p0 = lts[w * VC + l];
  float p1 = lts[w * VC + 64 + l];
  float p2 = lts[w * VC + 128 + l];
  float p3 = lts[w * VC + 192 + l];
  float m = wave_max(fmaxf(fmaxf(p0, p1), fmaxf(p2, p3)));
  float e0 = expf(p0 - m), e1 = expf(p1 - m), e2 = expf(p2 - m), e3 = expf(p3 - m);
  float Z = wave_sum(e0 + e1 + e2 + e3);
  probs_tok[tt * VC + l]       = e0 / Z;
  probs_tok[tt * VC + 64 + l]  = e1 / Z;
  probs_tok[tt * VC + 128 + l] = e2 / Z;
  probs_tok[tt * VC + 192 + l] = e3 / Z;
}

// K3: single-wave blocks. One 64-thread block per (b,tt): table row computed
// with wave-only reductions (thread owns vocab v = l+64j, j=0..3), attn
// slice built once in 8 f4v regs, logmix packed to one f4v/lane, then the
// identical row streamed to every position t with tokens[b][t]==tt.
__global__ __launch_bounds__(64) void kfused(
    const float* __restrict__ q_tok, const float* __restrict__ kT_P,
    const int* __restrict__ cnt, const int* __restrict__ ncnt,
    const int* __restrict__ offs, const int* __restrict__ list,
    const float* __restrict__ gate_tok, const float* __restrict__ probs_tok,
    const int* __restrict__ tokens, const int* __restrict__ prefix_lens,
    float* __restrict__ out_logmix, float* __restrict__ out_gate,
    float* __restrict__ out_attn)
{
  __shared__ __align__(16) float qs[AD];     // 256 B
  __shared__ __align__(16) float erow[VC];   // 1 KB
  __shared__ __align__(16) float lvs[VC];    // 1 KB
  const int b = blockIdx.x >> 8, tt = blockIdx.x & 255;
  const int l = threadIdx.x;  // 0..63

  // hoisted independent loads
  const int P = prefix_lens[b];
  const int4* tokrow = (const int4*)(tokens + b * SL);
  int4 tk[8];
#pragma unroll
  for (int i = 0; i < 8; ++i) tk[i] = tokrow[l + (i << 6)];
  const int nr = ncnt[b * VC + tt];
  const int base_off = offs[b * VC + tt];
  const float g = gate_tok[tt];
  int   c_[4];
  float pv[4];
#pragma unroll
  for (int j = 0; j < 4; ++j) {
    c_[j] = cnt[b * VC + l + (j << 6)];
    pv[j] = probs_tok[tt * VC + l + (j << 6)];
  }
  qs[l] = q_tok[tt * AD + l];
  __syncthreads();  // single wave: compiles to waitcnt + cheap barrier

  // scores for my 4 vocab ids
  const float4* qs4 = (const float4*)qs;
  const float4* k4p = (const float4*)kT_P;
  float sv[4] = {0.f, 0.f, 0.f, 0.f};
#pragma unroll
  for (int a4 = 0; a4 < AD / 4; ++a4) {
    float4 q4 = qs4[a4];
    sv[0] += dot44(q4, k4p[a4 * VC + l]);
    sv[1] += dot44(q4, k4p[a4 * VC + 64 + l]);
    sv[2] += dot44(q4, k4p[a4 * VC + 128 + l]);
    sv[3] += dot44(q4, k4p[a4 * VC + 192 + l]);
  }
  float mloc = -1e30f;
#pragma unroll
  for (int j = 0; j < 4; ++j) {
    sv[j] *= 0.125f;  // 1/sqrt(64)
    mloc = fmaxf(mloc, c_[j] > 0 ? sv[j] : -1e30f);
  }
  float m = wave_max(mloc);
  float e[4], zloc = 0.f;
#pragma unroll
  for (int j = 0; j < 4; ++j) {
    e[j] = expf(sv[j] - m);
    zloc += (float)c_[j] * e[j];
  }
  float Z = wave_sum(zloc);
#pragma unroll
  for (int j = 0; j < 4; ++j) {
    float en = e[j] / Z;
    erow[l + (j << 6)] = en;
    lvs[l + (j << 6)] =
        logf(fmaxf(g * pv[j] + (1.0f - g) * ((float)c_[j] * en), 1e-12f));
  }
  __syncthreads();

  // pack this lane's slices into registers
  f4v lv4 = ((const f4v*)lvs)[l];
  f4v a[8];
#pragma unroll
  for (int i = 0; i < 8; ++i) {
    int s0 = (l + (i << 6)) << 2;
    a[i].x = (s0     < P && tk[i].x != 0) ? erow[tk[i].x] : 0.0f;
    a[i].y = (s0 + 1 < P && tk[i].y != 0) ? erow[tk[i].y] : 0.0f;
    a[i].z = (s0 + 2 < P && tk[i].z != 0) ? erow[tk[i].z] : 0.0f;
    a[i].w = (s0 + 3 < P && tk[i].w != 0) ? erow[tk[i].w] : 0.0f;
  }

  // stream the identical row to every matching position
  const int* lp = list + b * SL + base_off;
  for (int r = 0; r < nr; ++r) {
    int t = lp[r];
    size_t row = (size_t)(b * SL + t);
    __builtin_nontemporal_store(lv4, &((f4v*)(out_logmix + row * VC))[l]);
    if (l == 0) out_gate[row] = g;
    f4v* ar = (f4v*)(out_attn + row * SL);
#pragma unroll
    for (int i = 0; i < 8; ++i)
      __builtin_nontemporal_store(a[i], &ar[l + (i << 6)]);
  }
}

extern "C" void kernel_launch(void* const* d_in, const int* in_sizes, int n_in,
                              void* d_out, int out_size, void* d_ws, size_t ws_size,
                              hipStream_t stream)
{
  const int*   tokens      = (const int*)  d_in[0];
  const int*   prefix_lens = (const int*)  d_in[1];
  const float* embed_w     = (const float*)d_in[2];
  const float* en_g        = (const float*)d_in[3];
  const float* en_b        = (const float*)d_in[4];
  const float* fn_g        = (const float*)d_in[5];
  const float* fn_b        = (const float*)d_in[6];
  const float* q_b         = (const float*)d_in[8];
  const float* k_b         = (const float*)d_in[10];
  const float* q_w         = (const float*)d_in[7];
  const float* k_w         = (const float*)d_in[9];
  const float* g_w         = (const float*)d_in[11];
  const float* g_b         = (const float*)d_in[12];

  // workspace layout (floats), all 16B-aligned offsets; ~1.3 MB total
  float* ws        = (float*)d_ws;
  float* embed_P   = ws;                        // 512*256 packed transpose
  float* qk_P      = embed_P + DM * VC;         // 512*128
  float* kT_P      = qk_P + DM * 128;           // 64*256
  float* q_tok     = kT_P + AD * VC;            // 256*64
  float* gate_tok  = q_tok + VC * AD;           // 256
  float* probs_tok = gate_tok + VC;             // 256*256
  int*   cnt       = (int*)(probs_tok + VC * VC);  // 8*256 masked counts
  int*   ncnt      = cnt + NB * VC;             // 8*256 full counts
  int*   offs      = ncnt + NB * VC;            // 8*256 exclusive offsets
  int*   list      = offs + NB * VC;            // 8*2048 position lists

  float* out_logmix = (float*)d_out;                      // 8*2048*256
  float* out_gate   = out_logmix + (size_t)NB * SL * VC;  // 8*2048
  float* out_attn   = out_gate + (size_t)NB * SL;         // 8*2048*2048

  kprep<<<DM + NB, 256, 0, stream>>>(embed_w, q_w, k_w, tokens, prefix_lens,
                                     embed_P, qk_P, cnt, ncnt, offs, list);
  ktok<<<VC / 4, 256, 0, stream>>>(embed_w, en_g, en_b, fn_g, fn_b, q_b, k_b,
                                   g_w, g_b, embed_P, qk_P,
                                   q_tok, kT_P, gate_tok, probs_tok);
  kfused<<<NB * VC, 64, 0, stream>>>(q_tok, kT_P, cnt, ncnt, offs, list,
                                     gate_tok, probs_tok, tokens, prefix_lens,
                                     out_logmix, out_gate, out_attn);
}

// Round 6
// 239.711 us; speedup vs baseline: 1.0467x; 1.0467x over previous
//
#include <hip/hip_runtime.h>
#include <math.h>

// CopyMamba3LM, token-id factorization (round 9 = resubmit of the round-4
// kernel; rounds 5 and 8 died in the broker before compile — no data).
// Budget model (confirmed 3x): timed region = 2 harness poison fills
// (~193 us, 604 MB @6.2-6.4 TB/s each, immovable) + ~44 us of our kernels.
// Floor: 151 MB mandatory output stores ~= 24-28 us + ~8-12 us small-kernel
// compute/launch => composite floor ~228-233 us.
// R5 post-mortem (250.9 us, +13.7 REGRESSION): ktok token-tile x4 used only
// 64/256 CUs (traded L2 bytes -- not scarce -- for CU coverage -- scarce);
// kfused 1-wave blocks lost store-stream MLP vs 4-wave blocks. Lesson:
// don't optimize counted quantities (barriers, L2 bytes) at the cost of
// uncounted ones (CU coverage, MLP).
// Pre-commitment: if this reproduces <=240 us, declare ROOFLINE next round.

#define DM 512
#define VC 256
#define SL 2048
#define NB 8
#define AD 64

typedef float f4v __attribute__((ext_vector_type(4)));

__device__ __forceinline__ float wave_sum(float v) {
#pragma unroll
  for (int o = 32; o > 0; o >>= 1) v += __shfl_xor(v, o, 64);
  return v;
}
__device__ __forceinline__ float wave_max(float v) {
#pragma unroll
  for (int o = 32; o > 0; o >>= 1) v = fmaxf(v, __shfl_xor(v, o, 64));
  return v;
}
// block = 256 threads = 4 waves
__device__ __forceinline__ float blk_sum(float v, float* red) {
  v = wave_sum(v);
  if ((threadIdx.x & 63) == 0) red[threadIdx.x >> 6] = v;
  __syncthreads();
  float r = red[0] + red[1] + red[2] + red[3];
  __syncthreads();
  return r;
}
__device__ __forceinline__ float blk_max(float v, float* red) {
  v = wave_max(v);
  if ((threadIdx.x & 63) == 0) red[threadIdx.x >> 6] = v;
  __syncthreads();
  float r = fmaxf(fmaxf(red[0], red[1]), fmaxf(red[2], red[3]));
  __syncthreads();
  return r;
}

// K1: pack transposed operands + per-batch token histogram/scan/position-lists.
__global__ __launch_bounds__(256) void kprep(
    const float* __restrict__ embed_w, const float* __restrict__ q_w,
    const float* __restrict__ k_w, const int* __restrict__ tokens,
    const int* __restrict__ prefix_lens,
    float* __restrict__ embed_P, float* __restrict__ qk_P,
    int* __restrict__ cnt, int* __restrict__ ncnt,
    int* __restrict__ offs, int* __restrict__ list)
{
  __shared__ int c[VC];    // masked (s < P) counts
  __shared__ int ca[VC];   // all-position counts
  __shared__ int off[VC];  // scan workspace -> exclusive offsets
  __shared__ int cur[VC];  // scatter cursors
  const int blk = blockIdx.x;
  const int tid = threadIdx.x;
  if (blk < DM) {
    const int d = blk;
    embed_P[(((d >> 2) * VC + tid) << 2) + (d & 3)] = embed_w[tid * DM + d];
    if (tid < 128) {
      float val = (tid < 64) ? q_w[tid * DM + d] : k_w[(tid - 64) * DM + d];
      qk_P[(((d >> 2) * 128 + tid) << 2) + (d & 3)] = val;
    }
  } else {
    const int b = blk - DM;
    c[tid] = 0; ca[tid] = 0;
    __syncthreads();
    const int P = prefix_lens[b];
    const int4* trow = (const int4*)(tokens + b * SL);
#pragma unroll
    for (int i = tid; i < SL / 4; i += 256) {
      int4 tk = trow[i];
      int s0 = i * 4;
      atomicAdd(&ca[tk.x], 1); atomicAdd(&ca[tk.y], 1);
      atomicAdd(&ca[tk.z], 1); atomicAdd(&ca[tk.w], 1);
      if (s0     < P && tk.x != 0) atomicAdd(&c[tk.x], 1);
      if (s0 + 1 < P && tk.y != 0) atomicAdd(&c[tk.y], 1);
      if (s0 + 2 < P && tk.z != 0) atomicAdd(&c[tk.z], 1);
      if (s0 + 3 < P && tk.w != 0) atomicAdd(&c[tk.w], 1);
    }
    __syncthreads();
    int myc = ca[tid];
    off[tid] = myc;
    __syncthreads();
    for (int d2 = 1; d2 < VC; d2 <<= 1) {
      int add = (tid >= d2) ? off[tid - d2] : 0;
      __syncthreads();
      off[tid] += add;
      __syncthreads();
    }
    int excl = off[tid] - myc;
    cur[tid] = excl;
    __syncthreads();
#pragma unroll
    for (int i = tid; i < SL / 4; i += 256) {
      int4 tk = trow[i];
      int s0 = i * 4;
      int p;
      p = atomicAdd(&cur[tk.x], 1); list[b * SL + p] = s0;
      p = atomicAdd(&cur[tk.y], 1); list[b * SL + p] = s0 + 1;
      p = atomicAdd(&cur[tk.z], 1); list[b * SL + p] = s0 + 2;
      p = atomicAdd(&cur[tk.w], 1); list[b * SL + p] = s0 + 3;
    }
    __syncthreads();
    cnt [b * VC + tid] = c[tid];
    ncnt[b * VC + tid] = myc;
    offs[b * VC + tid] = excl;
  }
}

// K2: per-token h = LN(LN(embed[tt])), gate, q row, k row (transposed packed),
// vocab logits + softmax. q/k dot and vocab dot share one pass over hs.
__global__ __launch_bounds__(256) void ktok(
    const float* __restrict__ embed_w,
    const float* __restrict__ en_g, const float* __restrict__ en_b,
    const float* __restrict__ fn_g, const float* __restrict__ fn_b,
    const float* __restrict__ q_b, const float* __restrict__ k_b,
    const float* __restrict__ g_w, const float* __restrict__ g_b,
    const float* __restrict__ embed_P, const float* __restrict__ qk_P,
    float* __restrict__ q_tok, float* __restrict__ kT_P,
    float* __restrict__ gate_tok, float* __restrict__ probs_tok)
{
  __shared__ float red[4];
  __shared__ __align__(16) float hs[DM];
  const int tt = blockIdx.x;    // token id
  const int tid = threadIdx.x;  // owns dims tid, tid+256

  float x0 = embed_w[tt * DM + tid];
  float x1 = embed_w[tt * DM + 256 + tid];
  // LN 1 (embed_norm)
  float mu = blk_sum(x0 + x1, red) * (1.0f / DM);
  float d0 = x0 - mu, d1 = x1 - mu;
  float var = blk_sum(d0 * d0 + d1 * d1, red) * (1.0f / DM);
  float inv = 1.0f / sqrtf(var + 1e-5f);
  float y0 = d0 * inv * en_g[tid] + en_b[tid];
  float y1 = d1 * inv * en_g[tid + 256] + en_b[tid + 256];
  // LN 2 (final_norm)
  mu = blk_sum(y0 + y1, red) * (1.0f / DM);
  d0 = y0 - mu; d1 = y1 - mu;
  var = blk_sum(d0 * d0 + d1 * d1, red) * (1.0f / DM);
  inv = 1.0f / sqrtf(var + 1e-5f);
  float h0 = d0 * inv * fn_g[tid] + fn_b[tid];
  float h1 = d1 * inv * fn_g[tid + 256] + fn_b[tid + 256];
  hs[tid] = h0; hs[tid + 256] = h1;
  // gate (blk_sum's barrier also publishes hs[])
  float gp = blk_sum(h0 * g_w[tid] + h1 * g_w[tid + 256], red);
  if (tid == 0) gate_tok[tt] = 1.0f / (1.0f + expf(-(gp + g_b[0])));

  const float4* hs4 = (const float4*)hs;
  const float4* w4p = (const float4*)qk_P;
  const float4* e4p = (const float4*)embed_P;
  const bool qk_lane = (tid < 128);  // wave-uniform (waves 0,1)
  float acc = 0.0f;  // q/k dot (threads 0..127)
  float lt = 0.0f;   // vocab logit (thread tid = vocab v)
#pragma unroll 8
  for (int d4 = 0; d4 < DM / 4; ++d4) {
    float4 h4 = hs4[d4];
    float4 e4 = e4p[d4 * VC + tid];
    lt += h4.x * e4.x + h4.y * e4.y + h4.z * e4.z + h4.w * e4.w;
    if (qk_lane) {
      float4 w4 = w4p[d4 * 128 + tid];
      acc += h4.x * w4.x + h4.y * w4.y + h4.z * w4.z + h4.w * w4.w;
    }
  }
  if (qk_lane) {
    if (tid < 64) {
      q_tok[tt * AD + tid] = acc + q_b[tid];
    } else {
      int a = tid - 64;
      kT_P[(((a >> 2) * VC + tt) << 2) + (a & 3)] = acc + k_b[a];
    }
  }
  // tied vocab head softmax
  float m = blk_max(lt, red);
  float e = expf(lt - m);
  float Z = blk_sum(e, red);
  probs_tok[tt * VC + tid] = e / Z;
}

// K3 (fused tables+writer, inverted): one block per (b,tt). Compute the
// masked-softmax table row once, build this thread's attn slice in
// REGISTERS (one gather per block, not per row), then stream the identical
// row to every position t with tokens[b][t]==tt. ~151 MB of NT stores.
__global__ __launch_bounds__(256) void kfused(
    const float* __restrict__ q_tok, const float* __restrict__ kT_P,
    const int* __restrict__ cnt, const int* __restrict__ ncnt,
    const int* __restrict__ offs, const int* __restrict__ list,
    const float* __restrict__ gate_tok, const float* __restrict__ probs_tok,
    const int* __restrict__ tokens, const int* __restrict__ prefix_lens,
    float* __restrict__ out_logmix, float* __restrict__ out_gate,
    float* __restrict__ out_attn)
{
  __shared__ float red[4];
  __shared__ __align__(16) float qs[AD];
  __shared__ __align__(16) float erow[VC];
  const int b = blockIdx.x >> 8, tt = blockIdx.x & 255;
  const int tid = threadIdx.x;  // = vocab v for the table phase

  // hoist independent loads (hide L2 latency under the dot/reductions)
  const int P = prefix_lens[b];
  const int4* tokrow = (const int4*)(tokens + b * SL);
  int4 tk0 = tokrow[tid];
  int4 tk1 = tokrow[tid + 256];
  const int nr = ncnt[b * VC + tt];
  const int base_off = offs[b * VC + tt];
  const float pv = probs_tok[tt * VC + tid];
  const float g = gate_tok[tt];
  if (tid < AD) qs[tid] = q_tok[tt * AD + tid];
  __syncthreads();

  const float4* qs4 = (const float4*)qs;
  const float4* k4p = (const float4*)kT_P;
  float sv = 0.0f;
#pragma unroll
  for (int a4 = 0; a4 < AD / 4; ++a4) {
    float4 q4 = qs4[a4];
    float4 k4 = k4p[a4 * VC + tid];
    sv += q4.x * k4.x + q4.y * k4.y + q4.z * k4.z + q4.w * k4.w;
  }
  sv *= 0.125f;  // 1/sqrt(64)
  int c = cnt[b * VC + tid];
  float m = blk_max(c > 0 ? sv : -1e30f, red);  // max over unmasked keys
  float e = expf(sv - m);
  float Z = blk_sum((float)c * e, red);
  float en = e / Z;
  erow[tid] = en;
  float lv = logf(fmaxf(g * pv + (1.0f - g) * ((float)c * en), 1e-12f));
  __syncthreads();  // publish erow

  // build this thread's attn slice once, in registers
  f4v a0, a1;
  {
    int s0 = tid * 4;
    a0.x = (s0     < P && tk0.x != 0) ? erow[tk0.x] : 0.0f;
    a0.y = (s0 + 1 < P && tk0.y != 0) ? erow[tk0.y] : 0.0f;
    a0.z = (s0 + 2 < P && tk0.z != 0) ? erow[tk0.z] : 0.0f;
    a0.w = (s0 + 3 < P && tk0.w != 0) ? erow[tk0.w] : 0.0f;
  }
  {
    int s0 = (tid + 256) * 4;
    a1.x = (s0     < P && tk1.x != 0) ? erow[tk1.x] : 0.0f;
    a1.y = (s0 + 1 < P && tk1.y != 0) ? erow[tk1.y] : 0.0f;
    a1.z = (s0 + 2 < P && tk1.z != 0) ? erow[tk1.z] : 0.0f;
    a1.w = (s0 + 3 < P && tk1.w != 0) ? erow[tk1.w] : 0.0f;
  }

  // stream the identical row to every matching position
  const int* lp = list + b * SL + base_off;
  for (int r = 0; r < nr; ++r) {
    int t = lp[r];
    size_t row = (size_t)(b * SL + t);
    __builtin_nontemporal_store(lv, &out_logmix[row * VC + tid]);
    if (tid == 0) out_gate[row] = g;
    f4v* ar = (f4v*)(out_attn + row * SL);
    __builtin_nontemporal_store(a0, &ar[tid]);
    __builtin_nontemporal_store(a1, &ar[tid + 256]);
  }
}

extern "C" void kernel_launch(void* const* d_in, const int* in_sizes, int n_in,
                              void* d_out, int out_size, void* d_ws, size_t ws_size,
                              hipStream_t stream)
{
  const int*   tokens      = (const int*)  d_in[0];
  const int*   prefix_lens = (const int*)  d_in[1];
  const float* embed_w     = (const float*)d_in[2];
  const float* en_g        = (const float*)d_in[3];
  const float* en_b        = (const float*)d_in[4];
  const float* fn_g        = (const float*)d_in[5];
  const float* fn_b        = (const float*)d_in[6];
  const float* q_b         = (const float*)d_in[8];
  const float* k_b         = (const float*)d_in[10];
  const float* q_w         = (const float*)d_in[7];
  const float* k_w         = (const float*)d_in[9];
  const float* g_w         = (const float*)d_in[11];
  const float* g_b         = (const float*)d_in[12];

  // workspace layout (floats), all 16B-aligned offsets; ~1.3 MB total
  float* ws        = (float*)d_ws;
  float* embed_P   = ws;                        // 512*256 packed transpose
  float* qk_P      = embed_P + DM * VC;         // 512*128
  float* kT_P      = qk_P + DM * 128;           // 64*256
  float* q_tok     = kT_P + AD * VC;            // 256*64
  float* gate_tok  = q_tok + VC * AD;           // 256
  float* probs_tok = gate_tok + VC;             // 256*256
  int*   cnt       = (int*)(probs_tok + VC * VC);  // 8*256 masked counts
  int*   ncnt      = cnt + NB * VC;             // 8*256 full counts
  int*   offs      = ncnt + NB * VC;            // 8*256 exclusive offsets
  int*   list      = offs + NB * VC;            // 8*2048 position lists

  float* out_logmix = (float*)d_out;                      // 8*2048*256
  float* out_gate   = out_logmix + (size_t)NB * SL * VC;  // 8*2048
  float* out_attn   = out_gate + (size_t)NB * SL;         // 8*2048*2048

  kprep<<<DM + NB, 256, 0, stream>>>(embed_w, q_w, k_w, tokens, prefix_lens,
                                     embed_P, qk_P, cnt, ncnt, offs, list);
  ktok<<<VC, 256, 0, stream>>>(embed_w, en_g, en_b, fn_g, fn_b, q_b, k_b,
                               g_w, g_b, embed_P, qk_P,
                               q_tok, kT_P, gate_tok, probs_tok);
  kfused<<<NB * VC, 256, 0, stream>>>(q_tok, kT_P, cnt, ncnt, offs, list,
                                      gate_tok, probs_tok, tokens, prefix_lens,
                                      out_logmix, out_gate, out_attn);
}